// Round 1
// baseline (846.693 us; speedup 1.0000x reference)
//
#include <hip/hip_runtime.h>

// Problem constants
#define IN_CAPS  1152
#define IN_DIM   8
#define NUM_CAPS 10
#define DIM_CAPS 16
#define B_TOT    256

#define I_T   36   // i's per block (32 i-tiles)
#define B_BLK 32   // batches per block (8 b-tiles); 2 per thread

// One routing sweep: recompute u_hat on the fly, softmax(u_hat·V) over n,
// accumulate s[b,n,d] via atomics. V=0 on the first sweep -> c uniform 0.1,
// exactly softmax(b=0).
__global__ __launch_bounds__(256) void pass_kernel(
    const float* __restrict__ x, const float* __restrict__ W,
    const float* __restrict__ Vbuf, float* __restrict__ sbuf) {
  const int tid = threadIdx.x;
  const int n   = tid & 15;        // capsule slot (10 active of 16)
  const int g   = tid >> 4;        // 0..15 -> batch pair
  const int b0  = blockIdx.x * B_BLK + 2 * g;
  const int i0  = blockIdx.y * I_T;
  const bool active = (n < NUM_CAPS);
  const int nn = active ? n : 0;   // clamp for safe (wasted) loads

  float V0[DIM_CAPS], V1[DIM_CAPS], s0[DIM_CAPS], s1[DIM_CAPS];
  const float* vp0 = Vbuf + (b0 * NUM_CAPS + nn) * DIM_CAPS;
  const float* vp1 = Vbuf + ((b0 + 1) * NUM_CAPS + nn) * DIM_CAPS;
#pragma unroll
  for (int d = 0; d < DIM_CAPS; ++d) {
    V0[d] = vp0[d]; V1[d] = vp1[d];
    s0[d] = 0.f;    s1[d] = 0.f;
  }

  const float4* __restrict__ Wp = (const float4*)W;
  const float4* __restrict__ xp = (const float4*)x;

  for (int i = i0; i < i0 + I_T; ++i) {
    // x[b,i,0:8] for the two batches (broadcast across the 16 n-lanes)
    float4 xa0 = xp[(size_t)(b0 * IN_CAPS + i) * 2];
    float4 xb0 = xp[(size_t)(b0 * IN_CAPS + i) * 2 + 1];
    float4 xa1 = xp[(size_t)((b0 + 1) * IN_CAPS + i) * 2];
    float4 xb1 = xp[(size_t)((b0 + 1) * IN_CAPS + i) * 2 + 1];

    const float4* wrow = Wp + (size_t)(nn * IN_CAPS + i) * 32;  // W[n,i,:,:]

    float u0[DIM_CAPS], u1[DIM_CAPS];
    float bd0 = 0.f, bd1 = 0.f;
#pragma unroll
    for (int d = 0; d < DIM_CAPS; ++d) {
      float4 wa = wrow[2 * d];
      float4 wb = wrow[2 * d + 1];
      float a = wa.x * xa0.x + wa.y * xa0.y + wa.z * xa0.z + wa.w * xa0.w
              + wb.x * xb0.x + wb.y * xb0.y + wb.z * xb0.z + wb.w * xb0.w;
      float c = wa.x * xa1.x + wa.y * xa1.y + wa.z * xa1.z + wa.w * xa1.w
              + wb.x * xb1.x + wb.y * xb1.y + wb.z * xb1.z + wb.w * xb1.w;
      u0[d] = a; u1[d] = c;
      bd0 += a * V0[d];
      bd1 += c * V1[d];
    }

    // softmax over n (10-wide; logits tiny so no max-subtraction needed)
    float e0 = active ? __expf(bd0) : 0.f;
    float e1 = active ? __expf(bd1) : 0.f;
    float es0 = e0, es1 = e1;
#pragma unroll
    for (int m = 1; m < 16; m <<= 1) {
      es0 += __shfl_xor(es0, m, 16);
      es1 += __shfl_xor(es1, m, 16);
    }
    float c0 = e0 / es0;
    float c1 = e1 / es1;
#pragma unroll
    for (int d = 0; d < DIM_CAPS; ++d) {
      s0[d] += c0 * u0[d];
      s1[d] += c1 * u1[d];
    }
  }

  if (active) {
    float* sp0 = sbuf + (b0 * NUM_CAPS + n) * DIM_CAPS;
    float* sp1 = sbuf + ((b0 + 1) * NUM_CAPS + n) * DIM_CAPS;
#pragma unroll
    for (int d = 0; d < DIM_CAPS; ++d) {
      atomicAdd(&sp0[d], s0[d]);
      atomicAdd(&sp1[d], s1[d]);
    }
  }
}

// v = squash(s); V += v (routing) or out = v (final); re-zero s.
__global__ void vupdate_kernel(float* __restrict__ sbuf, float* __restrict__ Vbuf,
                               float* __restrict__ out, int is_final) {
  const int b   = blockIdx.x;            // 0..255
  const int t   = threadIdx.x;           // 0..159 : n = t/16, d = t%16
  const int idx = b * (NUM_CAPS * DIM_CAPS) + t;
  float s  = sbuf[idx];
  float sq = s * s;
#pragma unroll
  for (int m = 1; m < 16; m <<= 1) sq += __shfl_xor(sq, m, 16);  // sum over d
  float norm = sqrtf(sq);
  float v = s * (sq / (1.f + sq)) / (norm + 1e-8f);
  if (is_final) {
    out[idx] = v;
  } else {
    Vbuf[idx] += v;
    sbuf[idx] = 0.f;
  }
}

extern "C" void kernel_launch(void* const* d_in, const int* in_sizes, int n_in,
                              void* d_out, int out_size, void* d_ws, size_t ws_size,
                              hipStream_t stream) {
  const float* x = (const float*)d_in[0];  // [256,1152,8]
  const float* W = (const float*)d_in[1];  // [1,10,1152,16,8]
  float* out  = (float*)d_out;             // [256,10,16]
  float* sbuf = (float*)d_ws;                          // 40960 floats
  float* Vbuf = (float*)d_ws + B_TOT * NUM_CAPS * DIM_CAPS;  // 40960 floats

  // zero s and V (ws is poisoned 0xAA before every call)
  hipMemsetAsync(d_ws, 0, (size_t)2 * B_TOT * NUM_CAPS * DIM_CAPS * sizeof(float), stream);

  for (int p = 0; p < 4; ++p) {
    pass_kernel<<<dim3(B_TOT / B_BLK, IN_CAPS / I_T), 256, 0, stream>>>(x, W, Vbuf, sbuf);
    vupdate_kernel<<<B_TOT, NUM_CAPS * DIM_CAPS, 0, stream>>>(sbuf, Vbuf, out, p == 3);
  }
}